// Round 2
// baseline (946.732 us; speedup 1.0000x reference)
//
#include <hip/hip_runtime.h>
#include <hip/hip_bf16.h>

typedef unsigned short u16;
typedef unsigned int u32;
typedef short bf16x8 __attribute__((ext_vector_type(8)));
typedef float f32x4 __attribute__((ext_vector_type(4)));

#define NTOK 8192
#define HID 768
#define INTER 2048
#define NEXP 8

#define MFMA16(a, b, c) __builtin_amdgcn_mfma_f32_16x16x32_bf16(a, b, c, 0, 0, 0)
#define S_BARRIER() __builtin_amdgcn_s_barrier()
#define SETPRIO(x) __builtin_amdgcn_s_setprio(x)
#define WAITVM(n) asm volatile("s_waitcnt vmcnt(" #n ")" ::: "memory")

__device__ __forceinline__ u16 f2bf(float f) {
    u32 u = __builtin_bit_cast(u32, f);
    u32 r = (u + 0x7FFFu + ((u >> 16) & 1u)) >> 16;
    return (u16)r;
}

__device__ __forceinline__ void gld16(const void* g, const void* l) {
    __builtin_amdgcn_global_load_lds((const __attribute__((address_space(1))) void*)g,
                                     (__attribute__((address_space(3))) void*)l, 16, 0, 0);
}

// ---------------- zero out + counts ----------------
__global__ __launch_bounds__(256) void zero_kernel(float4* out4, int n4, int* counts) {
    int i = blockIdx.x * blockDim.x + threadIdx.x;
    if (i < NEXP) counts[i] = 0;
    float4 z = {0.f, 0.f, 0.f, 0.f};
    int stride = gridDim.x * blockDim.x;
    for (int k = i; k < n4; k += stride) out4[k] = z;
}

// ---------------- fp32 -> bf16 convert (8 elems/iter) ----------------
__global__ __launch_bounds__(256) void cvt_kernel(const float* __restrict__ src, u16* __restrict__ dst, int n8) {
    int i = blockIdx.x * blockDim.x + threadIdx.x;
    int stride = gridDim.x * blockDim.x;
    for (; i < n8; i += stride) {
        const float4* s = (const float4*)(src + (size_t)i * 8);
        float4 a = s[0], b = s[1];
        u16 r[8] = {f2bf(a.x), f2bf(a.y), f2bf(a.z), f2bf(a.w),
                    f2bf(b.x), f2bf(b.y), f2bf(b.z), f2bf(b.w)};
        *(uint4*)(dst + (size_t)i * 8) = *(const uint4*)r;
    }
}

// ---------------- router: logits, top-2, softmax, scatter ----------------
__global__ __launch_bounds__(256) void router_kernel(const float* __restrict__ x, const float* __restrict__ rw,
                                                     int* counts, int* tokslot, float* wlist) {
    int wv = threadIdx.x >> 6, ln = threadIdx.x & 63;
    int t = blockIdx.x * 4 + wv;
    if (t >= NTOK) return;
    float xr[12];
#pragma unroll
    for (int j = 0; j < 12; j++) xr[j] = x[(size_t)t * HID + ln + j * 64];
    float lg[NEXP];
#pragma unroll
    for (int e = 0; e < NEXP; e++) {
        float a = 0.f;
#pragma unroll
        for (int j = 0; j < 12; j++) a += xr[j] * rw[e * HID + ln + j * 64];
#pragma unroll
        for (int off = 32; off; off >>= 1) a += __shfl_xor(a, off);
        lg[e] = a;
    }
    int i0 = 0;
    float v0 = lg[0];
#pragma unroll
    for (int e = 1; e < NEXP; e++)
        if (lg[e] > v0) { v0 = lg[e]; i0 = e; }
    int i1 = -1;
    float v1 = -1e30f;
#pragma unroll
    for (int e = 0; e < NEXP; e++) {
        if (e == i0) continue;
        if (lg[e] > v1) { v1 = lg[e]; i1 = e; }
    }
    float w0 = 1.f / (1.f + __expf(v1 - v0));
    float w1 = 1.f - w0;
    if (ln == 0) {
        int p0 = atomicAdd(&counts[i0], 1);
        tokslot[i0 * NTOK + p0] = t;
        wlist[i0 * NTOK + p0] = w0;
        int p1 = atomicAdd(&counts[i1], 1);
        tokslot[i1 * NTOK + p1] = t | (1 << 16);
        wlist[i1 * NTOK + p1] = w1;
    }
}

// =====================================================================
// 256x256-tile, BK=32, 8-wave (2x4), 4-buffer pipelined GEMM kernels.
// LDS per buf: A 256x32x2B = 16KB, B 16KB -> 32KB; 4 bufs = 128KB dynamic.
// Swizzle: byte-col ^= ((row&3)<<4), applied on global source (linear LDS
// dest, rule: both-sides involution) and on ds_read address.
// Pipeline: prefetch depth 3; counted vmcnt(8) once per K-tile; raw
// s_barrier (no vmcnt0 drain); setprio(1) around each 16-MFMA cluster.
// =====================================================================

#define ISSUE_A(buf, kt)                                           \
    do {                                                           \
        char* dA = lds + (buf)*32768 + tid * 16;                   \
        gld16(pA[0] + (size_t)(kt)*64, dA);                        \
        gld16(pA[1] + (size_t)(kt)*64, dA + 8192);                 \
    } while (0)
#define ISSUE_B(buf, kt)                                           \
    do {                                                           \
        char* dB = lds + (buf)*32768 + 16384 + tid * 16;           \
        gld16(pB[0] + (size_t)(kt)*64, dB);                        \
        gld16(pB[1] + (size_t)(kt)*64, dB + 8192);                 \
    } while (0)

#define PIPE_BODY(NKT)                                                        \
    f32x4 acc[8][4];                                                          \
    _Pragma("unroll") for (int m = 0; m < 8; m++)                             \
        _Pragma("unroll") for (int n = 0; n < 4; n++) acc[m][n] = (f32x4)0.f; \
    int aoff = (wr * 128 + rsel) * 64 + ((g4 * 16) ^ ((rsel & 3) << 4));      \
    int boff = (wc * 64 + rsel) * 64 + ((g4 * 16) ^ ((rsel & 3) << 4));       \
    ISSUE_A(0, 0); ISSUE_B(0, 0);                                             \
    ISSUE_A(1, 1); ISSUE_B(1, 1);                                             \
    ISSUE_A(2, 2); ISSUE_B(2, 2);                                             \
    WAITVM(8);                                                                \
    S_BARRIER();                                                              \
    for (int kt = 0; kt < (NKT); ++kt) {                                      \
        int buf = kt & 3;                                                     \
        const char* Ab = lds + buf * 32768;                                   \
        const char* Bb = Ab + 16384;                                          \
        bf16x8 af[4], bf[4];                                                  \
        _Pragma("unroll") for (int m = 0; m < 4; m++)                         \
            af[m] = *(const bf16x8*)(Ab + aoff + m * 1024);                   \
        _Pragma("unroll") for (int n = 0; n < 4; n++)                         \
            bf[n] = *(const bf16x8*)(Bb + boff + n * 1024);                   \
        if (kt + 3 < (NKT)) ISSUE_A((kt + 3) & 3, kt + 3);                    \
        S_BARRIER();                                                          \
        SETPRIO(1);                                                           \
        _Pragma("unroll") for (int m = 0; m < 4; m++)                         \
            _Pragma("unroll") for (int n = 0; n < 4; n++)                     \
                acc[m][n] = MFMA16(af[m], bf[n], acc[m][n]);                  \
        SETPRIO(0);                                                           \
        S_BARRIER();                                                          \
        _Pragma("unroll") for (int m = 0; m < 4; m++)                         \
            af[m] = *(const bf16x8*)(Ab + aoff + (m + 4) * 1024);             \
        if (kt + 3 < (NKT)) ISSUE_B((kt + 3) & 3, kt + 3);                    \
        if (kt <= (NKT)-4) { WAITVM(8); }                                     \
        else if (kt == (NKT)-3) { WAITVM(4); }                                \
        else if (kt == (NKT)-2) { WAITVM(0); }                                \
        S_BARRIER();                                                          \
        SETPRIO(1);                                                           \
        _Pragma("unroll") for (int m = 0; m < 4; m++)                         \
            _Pragma("unroll") for (int n = 0; n < 4; n++)                     \
                acc[m + 4][n] = MFMA16(af[m], bf[n], acc[m + 4][n]);          \
        SETPRIO(0);                                                           \
        S_BARRIER();                                                          \
    }

// ---------------- gate_up GEMM + swiglu -> h ----------------
// grid (32 row-tiles of 256, 16 col-tiles of 128 h-cols, 8 experts), 512 thr
__global__ __launch_bounds__(512, 2) void gateup8(const u16* __restrict__ xb, const u16* __restrict__ gub,
                                                  const int* __restrict__ counts,
                                                  const int* __restrict__ tokslot, u16* __restrict__ h) {
    int e = blockIdx.z;
    int cnt = counts[e];
    int row0 = blockIdx.x * 256;
    if (cnt == 0 || row0 >= cnt) return;
    int c0 = blockIdx.y * 128;

    extern __shared__ char lds[];
    int tid = threadIdx.x;
    int wv = tid >> 6, ln = tid & 63;
    int wr = wv >> 2, wc = wv & 3;
    int rsel = ln & 15, g4 = ln >> 4;

    // staging: portion q in {0,1}: LDS row = q*128 + (tid>>2), col byte = (tid&3)*16
    int srow = tid >> 2;
    int swz = ((tid & 3) << 4) ^ ((srow & 3) << 4);
    const char* pA[2];
    const char* pB[2];
    {
        int gr0 = row0 + srow; gr0 = gr0 < cnt ? gr0 : cnt - 1;
        int gr1 = row0 + 128 + srow; gr1 = gr1 < cnt ? gr1 : cnt - 1;
        int t0 = tokslot[e * NTOK + gr0] & 0xFFFF;
        int t1 = tokslot[e * NTOK + gr1] & 0xFFFF;
        pA[0] = (const char*)xb + (size_t)t0 * (HID * 2) + swz;
        pA[1] = (const char*)xb + (size_t)t1 * (HID * 2) + swz;
        // B row r -> gu row: [wc-group of 64][32 gate | 32 up] per group
        int r0 = srow, r1 = 128 + srow;
        int wi0 = r0 & 63, wi1 = r1 & 63;
        int b0 = (wi0 >> 5) * 2048 + c0 + (r0 >> 6) * 32 + (wi0 & 31);
        int b1 = (wi1 >> 5) * 2048 + c0 + (r1 >> 6) * 32 + (wi1 & 31);
        pB[0] = (const char*)gub + ((size_t)e * 4096 + b0) * (HID * 2) + swz;
        pB[1] = (const char*)gub + ((size_t)e * 4096 + b1) * (HID * 2) + swz;
    }

    PIPE_BODY(HID / 32)

    // epilogue: n in {0,1} = gate, n+2 = matching up; hcol = c0 + wc*32 + n*16 + rsel
#pragma unroll
    for (int m = 0; m < 8; m++) {
#pragma unroll
        for (int j = 0; j < 4; j++) {
            int gr = row0 + wr * 128 + m * 16 + g4 * 4 + j;
            if (gr >= cnt) continue;
            int ts = tokslot[e * NTOK + gr];
            int tok = ts & 0xFFFF, slot = ts >> 16;
            u16* hrow = h + (size_t)(slot * NTOK + tok) * INTER;
#pragma unroll
            for (int n = 0; n < 2; n++) {
                float gv = acc[m][n][j];
                float uv = fminf(acc[m][n + 2][j], 7.0f);
                float sg = gv / (1.0f + __expf(-gv));
                hrow[c0 + wc * 32 + n * 16 + rsel] = f2bf(sg * uv);
            }
        }
    }
}

// ---------------- down GEMM + weighted scatter-add ----------------
// grid (32 row-tiles of 256, 3 col-tiles of 256, 8 experts), 512 thr
__global__ __launch_bounds__(512, 2) void down8(const u16* __restrict__ hb, const u16* __restrict__ dnb,
                                                const int* __restrict__ counts,
                                                const int* __restrict__ tokslot,
                                                const float* __restrict__ wlist, float* __restrict__ out) {
    int e = blockIdx.z;
    int cnt = counts[e];
    int row0 = blockIdx.x * 256;
    if (cnt == 0 || row0 >= cnt) return;
    int col0 = blockIdx.y * 256;

    extern __shared__ char lds[];
    int tid = threadIdx.x;
    int wv = tid >> 6, ln = tid & 63;
    int wr = wv >> 2, wc = wv & 3;
    int rsel = ln & 15, g4 = ln >> 4;

    int srow = tid >> 2;
    int swz = ((tid & 3) << 4) ^ ((srow & 3) << 4);
    const char* pA[2];
    const char* pB[2];
    {
        int gr0 = row0 + srow; gr0 = gr0 < cnt ? gr0 : cnt - 1;
        int gr1 = row0 + 128 + srow; gr1 = gr1 < cnt ? gr1 : cnt - 1;
        int ts0 = tokslot[e * NTOK + gr0];
        int ts1 = tokslot[e * NTOK + gr1];
        pA[0] = (const char*)hb + (size_t)((ts0 >> 16) * NTOK + (ts0 & 0xFFFF)) * (INTER * 2) + swz;
        pA[1] = (const char*)hb + (size_t)((ts1 >> 16) * NTOK + (ts1 & 0xFFFF)) * (INTER * 2) + swz;
        pB[0] = (const char*)dnb + ((size_t)e * HID + col0 + srow) * (INTER * 2) + swz;
        pB[1] = (const char*)dnb + ((size_t)e * HID + col0 + 128 + srow) * (INTER * 2) + swz;
    }

    PIPE_BODY(INTER / 32)

#pragma unroll
    for (int m = 0; m < 8; m++) {
#pragma unroll
        for (int j = 0; j < 4; j++) {
            int gr = row0 + wr * 128 + m * 16 + g4 * 4 + j;
            if (gr >= cnt) continue;
            int ts = tokslot[e * NTOK + gr];
            int tok = ts & 0xFFFF;
            float w = wlist[e * NTOK + gr];
#pragma unroll
            for (int n = 0; n < 4; n++) {
                int col = col0 + wc * 64 + n * 16 + rsel;
                atomicAdd(&out[(size_t)tok * HID + col], w * acc[m][n][j]);
            }
        }
    }
}

// ---------------- launch ----------------
extern "C" void kernel_launch(void* const* d_in, const int* in_sizes, int n_in,
                              void* d_out, int out_size, void* d_ws, size_t ws_size,
                              hipStream_t stream) {
    const float* x = (const float*)d_in[0];
    const float* rw = (const float*)d_in[1];
    const float* gu = (const float*)d_in[2];
    const float* dn = (const float*)d_in[3];
    float* out = (float*)d_out;
    char* ws = (char*)d_ws;

    int* counts = (int*)(ws + 0);
    int* tokslot = (int*)(ws + 256);
    float* wlist = (float*)(ws + 262400);
    u16* xb = (u16*)(ws + 524544);
    u16* gub = (u16*)(ws + 13107456);
    u16* dnb = (u16*)(ws + 63439104);
    u16* hb = (u16*)(ws + 88604928);

    zero_kernel<<<1024, 256, 0, stream>>>((float4*)out, NTOK * HID / 4, counts);
    cvt_kernel<<<2048, 256, 0, stream>>>(x, xb, NTOK * HID / 8);
    cvt_kernel<<<2048, 256, 0, stream>>>(gu, gub, NEXP * 2 * INTER * HID / 8);
    cvt_kernel<<<2048, 256, 0, stream>>>(dn, dnb, NEXP * HID * INTER / 8);
    router_kernel<<<NTOK / 4, 256, 0, stream>>>(x, rw, counts, tokslot, wlist);
    gateup8<<<dim3(32, 16, 8), 512, 131072, stream>>>(xb, gub, counts, tokslot, hb);
    down8<<<dim3(32, 3, 8), 512, 131072, stream>>>(hb, dnb, counts, tokslot, wlist, out);
}

// Round 3
// 596.818 us; speedup vs baseline: 1.5863x; 1.5863x over previous
//
#include <hip/hip_runtime.h>
#include <hip/hip_bf16.h>

typedef unsigned short u16;
typedef unsigned int u32;
typedef short bf16x8 __attribute__((ext_vector_type(8)));
typedef float f32x4 __attribute__((ext_vector_type(4)));

#define NTOK 8192
#define HID 768
#define INTER 2048
#define NEXP 8

#define MFMA16(a, b, c) __builtin_amdgcn_mfma_f32_16x16x32_bf16(a, b, c, 0, 0, 0)
#define S_BARRIER() __builtin_amdgcn_s_barrier()
#define SETPRIO(x) __builtin_amdgcn_s_setprio(x)
#define WAITVM(n) asm volatile("s_waitcnt vmcnt(" #n ")" ::: "memory")

__device__ __forceinline__ u16 f2bf(float f) {
    u32 u = __builtin_bit_cast(u32, f);
    u32 r = (u + 0x7FFFu + ((u >> 16) & 1u)) >> 16;
    return (u16)r;
}

__device__ __forceinline__ void gld16(const void* g, void* l) {
    __builtin_amdgcn_global_load_lds((const __attribute__((address_space(1))) void*)g,
                                     (__attribute__((address_space(3))) void*)l, 16, 0, 0);
}

// ---------------- zero counts ----------------
__global__ void zero_counts(int* counts) {
    if (threadIdx.x < NEXP) counts[threadIdx.x] = 0;
}

// ---------------- fp32 -> bf16 convert ----------------
__global__ __launch_bounds__(256) void cvt_kernel(const float* __restrict__ src, u16* __restrict__ dst, int n8) {
    int i = blockIdx.x * blockDim.x + threadIdx.x;
    int stride = gridDim.x * blockDim.x;
    for (; i < n8; i += stride) {
        const float4* s = (const float4*)(src + (size_t)i * 8);
        float4 a = s[0], b = s[1];
        u16 r[8] = {f2bf(a.x), f2bf(a.y), f2bf(a.z), f2bf(a.w),
                    f2bf(b.x), f2bf(b.y), f2bf(b.z), f2bf(b.w)};
        *(uint4*)(dst + (size_t)i * 8) = *(const uint4*)r;
    }
}

// ---------------- router ----------------
__global__ __launch_bounds__(256) void router_kernel(const float* __restrict__ x, const float* __restrict__ rw,
                                                     int* counts, int* tokslot, float* wslot) {
    int wv = threadIdx.x >> 6, ln = threadIdx.x & 63;
    int t = blockIdx.x * 4 + wv;
    if (t >= NTOK) return;
    float xr[12];
#pragma unroll
    for (int j = 0; j < 12; j++) xr[j] = x[(size_t)t * HID + ln + j * 64];
    float lg[NEXP];
#pragma unroll
    for (int e = 0; e < NEXP; e++) {
        float a = 0.f;
#pragma unroll
        for (int j = 0; j < 12; j++) a += xr[j] * rw[e * HID + ln + j * 64];
#pragma unroll
        for (int off = 32; off; off >>= 1) a += __shfl_xor(a, off);
        lg[e] = a;
    }
    int i0 = 0;
    float v0 = lg[0];
#pragma unroll
    for (int e = 1; e < NEXP; e++)
        if (lg[e] > v0) { v0 = lg[e]; i0 = e; }
    int i1 = -1;
    float v1 = -1e30f;
#pragma unroll
    for (int e = 0; e < NEXP; e++) {
        if (e == i0) continue;
        if (lg[e] > v1) { v1 = lg[e]; i1 = e; }
    }
    float w0 = 1.f / (1.f + __expf(v1 - v0));
    float w1 = 1.f - w0;
    if (ln == 0) {
        wslot[0 * NTOK + t] = w0;
        wslot[1 * NTOK + t] = w1;
        int p0 = atomicAdd(&counts[i0], 1);
        tokslot[i0 * NTOK + p0] = t;
        int p1 = atomicAdd(&counts[i1], 1);
        tokslot[i1 * NTOK + p1] = t | (1 << 16);
    }
}

// =====================================================================
// 8-phase k-split pipelined 256x256 GEMM template.
// LDS: 2 bufs x {A,B} x 2 k-halves x (256 rows x 64B) = 128 KiB.
// Quarter liveness (iter j): buf0.k0 read p0-p1, buf0.k1 p2-p3,
// buf1.k0 p4-p5, buf1.k1 p6-p7. Stages: p0/p1: buf1.k1<-tile 2j+1;
// p2/p3: buf0.k0<-2j+2; p4/p5: buf0.k1<-2j+2; p6/p7: buf1.k0<-2j+3.
// vmcnt(8) at odd phases drains exactly the quarter-pair needed by the
// following even phase (6-phase stage-to-read distance; never vmcnt(0)).
// Swizzle: 16B slot ^= (row&3), applied to global source (LDS dest linear,
// both-sides involution) and to the ds_read address.
// =====================================================================

#define QOFF(d, ab, kh) ((d)*65536 + (ab)*32768 + (kh)*16384)

#define STAGE(qo, p0, p1, ko)                        \
    do {                                             \
        char* dst_ = lds + (qo) + tid * 16;          \
        gld16((p0) + (ko), dst_);                    \
        gld16((p1) + (ko), dst_ + 8192);             \
    } while (0)

#define RD_A(d, kh, mh)                                                   \
    do {                                                                  \
        const char* Ab_ = lds + QOFF(d, 0, kh) + aOff;                    \
        af[0] = *(const bf16x8*)(Ab_ + ((mh)*4 + 0) * 1024);              \
        af[1] = *(const bf16x8*)(Ab_ + ((mh)*4 + 1) * 1024);              \
        af[2] = *(const bf16x8*)(Ab_ + ((mh)*4 + 2) * 1024);              \
        af[3] = *(const bf16x8*)(Ab_ + ((mh)*4 + 3) * 1024);              \
    } while (0)

#define RD_B(d, kh)                                                       \
    do {                                                                  \
        const char* Bb_ = lds + QOFF(d, 1, kh) + bOff;                    \
        bf[0] = *(const bf16x8*)(Bb_ + 0 * 1024);                         \
        bf[1] = *(const bf16x8*)(Bb_ + 1 * 1024);                         \
        bf[2] = *(const bf16x8*)(Bb_ + 2 * 1024);                         \
        bf[3] = *(const bf16x8*)(Bb_ + 3 * 1024);                         \
    } while (0)

#define MM(mh)                                                            \
    do {                                                                  \
        _Pragma("unroll") for (int m_ = 0; m_ < 4; m_++)                  \
            _Pragma("unroll") for (int n_ = 0; n_ < 4; n_++)              \
                acc[(mh)*4 + m_][n_] = MFMA16(af[m_], bf[n_], acc[(mh)*4 + m_][n_]); \
    } while (0)

#define PHASE_PAIR(dR, khR, qoE, pE0, pE1, koE, qoO, pO0, pO1, koO)       \
    do {                                                                  \
        bf16x8 af[4], bf[4];                                              \
        RD_A(dR, khR, 0);                                                 \
        RD_B(dR, khR);                                                    \
        STAGE(qoE, pE0, pE1, koE);                                        \
        S_BARRIER();                                                      \
        SETPRIO(1); MM(0); SETPRIO(0);                                    \
        S_BARRIER();                                                      \
        RD_A(dR, khR, 1);                                                 \
        STAGE(qoO, pO0, pO1, koO);                                        \
        WAITVM(8);                                                        \
        S_BARRIER();                                                      \
        SETPRIO(1); MM(1); SETPRIO(0);                                    \
        S_BARRIER();                                                      \
    } while (0)

#define PIPE8(NKT)                                                        \
    f32x4 acc[8][4];                                                      \
    _Pragma("unroll") for (int m_ = 0; m_ < 8; m_++)                      \
        _Pragma("unroll") for (int n_ = 0; n_ < 4; n_++) acc[m_][n_] = (f32x4)0.f; \
    int aOff = (wr * 128 + rsel) * 64 + ((g4 ^ (rsel & 3)) << 4);         \
    int bOff = (wc * 64 + rsel) * 64 + ((g4 ^ (rsel & 3)) << 4);          \
    STAGE(QOFF(0, 0, 0), aP0, aP1, 0);                                    \
    STAGE(QOFF(0, 1, 0), bP0, bP1, 0);                                    \
    STAGE(QOFF(0, 0, 1), aP0, aP1, 64);                                   \
    STAGE(QOFF(0, 1, 1), bP0, bP1, 64);                                   \
    STAGE(QOFF(1, 0, 0), aP0, aP1, 128);                                  \
    STAGE(QOFF(1, 1, 0), bP0, bP1, 128);                                  \
    WAITVM(8);                                                            \
    S_BARRIER();                                                          \
    for (int j = 0; j < (NKT) / 2; ++j) {                                 \
        int t1k = (2 * j + 1) * 128 + 64;                                 \
        int t2 = 2 * j + 2; if (t2 >= (NKT)) t2 = 0;                      \
        int t3 = 2 * j + 3; if (t3 >= (NKT)) t3 = 1;                      \
        int t2k0 = t2 * 128, t2k1 = t2 * 128 + 64, t3k0 = t3 * 128;       \
        PHASE_PAIR(0, 0, QOFF(1, 0, 1), aP0, aP1, t1k, QOFF(1, 1, 1), bP0, bP1, t1k);   \
        PHASE_PAIR(0, 1, QOFF(0, 0, 0), aP0, aP1, t2k0, QOFF(0, 1, 0), bP0, bP1, t2k0); \
        PHASE_PAIR(1, 0, QOFF(0, 0, 1), aP0, aP1, t2k1, QOFF(0, 1, 1), bP0, bP1, t2k1); \
        PHASE_PAIR(1, 1, QOFF(1, 0, 0), aP0, aP1, t3k0, QOFF(1, 1, 0), bP0, bP1, t3k0); \
    }                                                                     \
    WAITVM(0);                                                            \
    S_BARRIER();

// ---------------- gate_up GEMM + swiglu -> h ----------------
// logical grid: 32 row-tiles x 16 col-tiles (128 h-cols) x 8 experts; XCD-swizzled
__global__ __launch_bounds__(512, 2) void gateup8p(const u16* __restrict__ xb, const u16* __restrict__ gub,
                                                   const int* __restrict__ counts,
                                                   const int* __restrict__ tokslot, u16* __restrict__ h) {
    int e = blockIdx.z;
    int cnt = counts[e];
    // XCD-aware remap: XCD c = bx&7 gets y-tiles {2c,2c+1} for all row-tiles
    int c = blockIdx.x & 7;
    int rr = (blockIdx.x >> 3) + 4 * blockIdx.y;  // [0,64)
    int xt = rr & 31;
    int yt = (rr >> 5) + 2 * c;                   // [0,16)
    int row0 = xt * 256;
    if (cnt == 0 || row0 >= cnt) return;
    int c0 = yt * 128;

    extern __shared__ char lds[];
    int tid = threadIdx.x;
    int wv = tid >> 6, ln = tid & 63;
    int wr = wv >> 2, wc = wv & 3;
    int rsel = ln & 15, g4 = ln >> 4;

    // staging sources: thread covers rows (tid>>2) and 128+(tid>>2), slot tid&3
    int srow = tid >> 2, sl = tid & 3;
    int sx = ((sl ^ (srow & 3)) << 4);
    const char* aP0;
    const char* aP1;
    const char* bP0;
    const char* bP1;
    {
        int gr0 = row0 + srow; gr0 = gr0 < cnt ? gr0 : cnt - 1;
        int gr1 = row0 + 128 + srow; gr1 = gr1 < cnt ? gr1 : cnt - 1;
        int t0 = tokslot[e * NTOK + gr0] & 0xFFFF;
        int t1 = tokslot[e * NTOK + gr1] & 0xFFFF;
        aP0 = (const char*)xb + (size_t)t0 * (HID * 2) + sx;
        aP1 = (const char*)xb + (size_t)t1 * (HID * 2) + sx;
        // B row r: group wc=r>>6, wi=r&63; wi<32 -> gate col c0+wc*32+wi, else up
        int r0 = srow, r1 = 128 + srow;
        int wi0 = r0 & 63, wi1 = r1 & 63;
        int b0 = (wi0 >> 5) * 2048 + c0 + (r0 >> 6) * 32 + (wi0 & 31);
        int b1 = (wi1 >> 5) * 2048 + c0 + (r1 >> 6) * 32 + (wi1 & 31);
        bP0 = (const char*)gub + ((size_t)e * 4096 + b0) * (HID * 2) + sx;
        bP1 = (const char*)gub + ((size_t)e * 4096 + b1) * (HID * 2) + sx;
    }

    PIPE8(HID / 64)  // 12 K-tiles

    // epilogue: n in {0,1}=gate, n+2=up; h-col = c0 + wc*32 + n*16 + rsel
#pragma unroll
    for (int mg = 0; mg < 8; mg++) {
#pragma unroll
        for (int j = 0; j < 4; j++) {
            int gr = row0 + wr * 128 + mg * 16 + g4 * 4 + j;
            if (gr >= cnt) continue;
            int ts = tokslot[e * NTOK + gr];
            int tok = ts & 0xFFFF, slot = ts >> 16;
            u16* hrow = h + (size_t)(slot * NTOK + tok) * INTER;
#pragma unroll
            for (int n = 0; n < 2; n++) {
                float gv = acc[mg][n][j];
                float uv = fminf(acc[mg][n + 2][j], 7.0f);
                float sg = gv / (1.0f + __expf(-gv));
                hrow[c0 + wc * 32 + n * 16 + rsel] = f2bf(sg * uv);
            }
        }
    }
}

// ---------------- down GEMM -> per-slot partials (no atomics) ----------------
// grid (32 row-tiles, 3 col-tiles of 256, 8 experts)
__global__ __launch_bounds__(512, 2) void down8p(const u16* __restrict__ hb, const u16* __restrict__ dnb,
                                                 const int* __restrict__ counts,
                                                 const int* __restrict__ tokslot,
                                                 const float* __restrict__ wslot, float* __restrict__ dsout) {
    int e = blockIdx.z;
    int cnt = counts[e];
    int row0 = blockIdx.x * 256;
    if (cnt == 0 || row0 >= cnt) return;
    int col0 = blockIdx.y * 256;

    extern __shared__ char lds[];
    int tid = threadIdx.x;
    int wv = tid >> 6, ln = tid & 63;
    int wr = wv >> 2, wc = wv & 3;
    int rsel = ln & 15, g4 = ln >> 4;

    int srow = tid >> 2, sl = tid & 3;
    int sx = ((sl ^ (srow & 3)) << 4);
    const char* aP0;
    const char* aP1;
    const char* bP0;
    const char* bP1;
    {
        int gr0 = row0 + srow; gr0 = gr0 < cnt ? gr0 : cnt - 1;
        int gr1 = row0 + 128 + srow; gr1 = gr1 < cnt ? gr1 : cnt - 1;
        int ts0 = tokslot[e * NTOK + gr0];
        int ts1 = tokslot[e * NTOK + gr1];
        aP0 = (const char*)hb + (size_t)((ts0 >> 16) * NTOK + (ts0 & 0xFFFF)) * (INTER * 2) + sx;
        aP1 = (const char*)hb + (size_t)((ts1 >> 16) * NTOK + (ts1 & 0xFFFF)) * (INTER * 2) + sx;
        bP0 = (const char*)dnb + ((size_t)e * HID + col0 + srow) * (INTER * 2) + sx;
        bP1 = (const char*)dnb + ((size_t)e * HID + col0 + 128 + srow) * (INTER * 2) + sx;
    }

    PIPE8(INTER / 64)  // 32 K-tiles

#pragma unroll
    for (int mg = 0; mg < 8; mg++) {
#pragma unroll
        for (int j = 0; j < 4; j++) {
            int gr = row0 + wr * 128 + mg * 16 + g4 * 4 + j;
            if (gr >= cnt) continue;
            int ts = tokslot[e * NTOK + gr];
            int tok = ts & 0xFFFF, slot = ts >> 16;
            float w = wslot[slot * NTOK + tok];
            float* orow = dsout + (size_t)(slot * NTOK + tok) * HID;
#pragma unroll
            for (int n = 0; n < 4; n++) {
                orow[col0 + wc * 64 + n * 16 + rsel] = w * acc[mg][n][j];
            }
        }
    }
}

// ---------------- combine: out = ds0 + ds1 ----------------
__global__ __launch_bounds__(256) void combine_kernel(const float4* __restrict__ a, const float4* __restrict__ b,
                                                      float4* __restrict__ o, int n4) {
    int i = blockIdx.x * blockDim.x + threadIdx.x;
    int stride = gridDim.x * blockDim.x;
    for (; i < n4; i += stride) {
        float4 va = a[i], vb = b[i];
        o[i] = make_float4(va.x + vb.x, va.y + vb.y, va.z + vb.z, va.w + vb.w);
    }
}

// ---------------- launch ----------------
extern "C" void kernel_launch(void* const* d_in, const int* in_sizes, int n_in,
                              void* d_out, int out_size, void* d_ws, size_t ws_size,
                              hipStream_t stream) {
    const float* x = (const float*)d_in[0];
    const float* rw = (const float*)d_in[1];
    const float* gu = (const float*)d_in[2];
    const float* dn = (const float*)d_in[3];
    float* out = (float*)d_out;
    char* ws = (char*)d_ws;

    // workspace layout (bytes)
    int* counts = (int*)(ws + 0);                   // 32
    int* tokslot = (int*)(ws + 256);                // 8*8192*4 = 262144
    float* wslot = (float*)(ws + 262400);           // 2*8192*4 = 65536
    u16* xb = (u16*)(ws + 327936);                  // 12,582,912
    u16* gub = (u16*)(ws + 12910848);               // 50,331,648
    u16* dnb = (u16*)(ws + 63242496);               // 25,165,824
    u16* hb = (u16*)(ws + 88408320);                // 67,108,864 -> ends 155,517,184
    float* dsout = (float*)(ws + 327936);           // 50,331,648 (aliases xb+gub; dead by then)

    zero_counts<<<1, 64, 0, stream>>>(counts);
    cvt_kernel<<<2048, 256, 0, stream>>>(x, xb, NTOK * HID / 8);
    cvt_kernel<<<2048, 256, 0, stream>>>(gu, gub, NEXP * 2 * INTER * HID / 8);
    cvt_kernel<<<2048, 256, 0, stream>>>(dn, dnb, NEXP * HID * INTER / 8);
    router_kernel<<<NTOK / 4, 256, 0, stream>>>(x, rw, counts, tokslot, wslot);
    gateup8p<<<dim3(32, 16, 8), 512, 131072, stream>>>(xb, gub, counts, tokslot, hb);
    down8p<<<dim3(32, 3, 8), 512, 131072, stream>>>(hb, dnb, counts, tokslot, wslot, dsout);
    combine_kernel<<<2048, 256, 0, stream>>>((const float4*)dsout, (const float4*)(dsout + NTOK * HID),
                                             (float4*)out, NTOK * HID / 4);
}

// Round 4
// 497.116 us; speedup vs baseline: 1.9044x; 1.2006x over previous
//
#include <hip/hip_runtime.h>
#include <hip/hip_bf16.h>

typedef unsigned short u16;
typedef unsigned int u32;
typedef short bf16x8 __attribute__((ext_vector_type(8)));
typedef float f32x4 __attribute__((ext_vector_type(4)));

#define NTOK 8192
#define HID 768
#define INTER 2048
#define NEXP 8

#define MFMA16(a, b, c) __builtin_amdgcn_mfma_f32_16x16x32_bf16(a, b, c, 0, 0, 0)
#define S_BARRIER() __builtin_amdgcn_s_barrier()
#define SETPRIO(x) __builtin_amdgcn_s_setprio(x)
#define WAITVM(n) asm volatile("s_waitcnt vmcnt(" #n ")" ::: "memory")

__device__ __forceinline__ u16 f2bf(float f) {
    u32 u = __builtin_bit_cast(u32, f);
    u32 r = (u + 0x7FFFu + ((u >> 16) & 1u)) >> 16;
    return (u16)r;
}

__device__ __forceinline__ void gld16(const void* g, void* l) {
    __builtin_amdgcn_global_load_lds((const __attribute__((address_space(1))) void*)g,
                                     (__attribute__((address_space(3))) void*)l, 16, 0, 0);
}

// ---------------- zero out + counts ----------------
__global__ __launch_bounds__(256) void zero_kernel(float4* out4, int n4, int* counts) {
    int i = blockIdx.x * blockDim.x + threadIdx.x;
    if (i < NEXP) counts[i] = 0;
    float4 z = {0.f, 0.f, 0.f, 0.f};
    int stride = gridDim.x * blockDim.x;
    for (int k = i; k < n4; k += stride) out4[k] = z;
}

// ---------------- fp32 -> bf16 convert ----------------
__global__ __launch_bounds__(256) void cvt_kernel(const float* __restrict__ src, u16* __restrict__ dst, int n8) {
    int i = blockIdx.x * blockDim.x + threadIdx.x;
    int stride = gridDim.x * blockDim.x;
    for (; i < n8; i += stride) {
        const float4* s = (const float4*)(src + (size_t)i * 8);
        float4 a = s[0], b = s[1];
        u16 r[8] = {f2bf(a.x), f2bf(a.y), f2bf(a.z), f2bf(a.w),
                    f2bf(b.x), f2bf(b.y), f2bf(b.z), f2bf(b.w)};
        *(uint4*)(dst + (size_t)i * 8) = *(const uint4*)r;
    }
}

// ---------------- router ----------------
__global__ __launch_bounds__(256) void router_kernel(const float* __restrict__ x, const float* __restrict__ rw,
                                                     int* counts, int* tokslot, float* wslot) {
    int wv = threadIdx.x >> 6, ln = threadIdx.x & 63;
    int t = blockIdx.x * 4 + wv;
    if (t >= NTOK) return;
    float xr[12];
#pragma unroll
    for (int j = 0; j < 12; j++) xr[j] = x[(size_t)t * HID + ln + j * 64];
    float lg[NEXP];
#pragma unroll
    for (int e = 0; e < NEXP; e++) {
        float a = 0.f;
#pragma unroll
        for (int j = 0; j < 12; j++) a += xr[j] * rw[e * HID + ln + j * 64];
#pragma unroll
        for (int off = 32; off; off >>= 1) a += __shfl_xor(a, off);
        lg[e] = a;
    }
    int i0 = 0;
    float v0 = lg[0];
#pragma unroll
    for (int e = 1; e < NEXP; e++)
        if (lg[e] > v0) { v0 = lg[e]; i0 = e; }
    int i1 = -1;
    float v1 = -1e30f;
#pragma unroll
    for (int e = 0; e < NEXP; e++) {
        if (e == i0) continue;
        if (lg[e] > v1) { v1 = lg[e]; i1 = e; }
    }
    float w0 = 1.f / (1.f + __expf(v1 - v0));
    float w1 = 1.f - w0;
    if (ln == 0) {
        wslot[0 * NTOK + t] = w0;
        wslot[1 * NTOK + t] = w1;
        int p0 = atomicAdd(&counts[i0], 1);
        tokslot[i0 * NTOK + p0] = t;
        int p1 = atomicAdd(&counts[i1], 1);
        tokslot[i1 * NTOK + p1] = t | (1 << 16);
    }
}

// ---------------- schedule: dense (expert,row-tile) descriptor list ----------------
__global__ void sched_kernel(const int* __restrict__ counts, int* ntiles, int* tiledesc) {
    if (threadIdx.x == 0) {
        int tot = 0;
        for (int e = 0; e < NEXP; e++) {
            int nt = (counts[e] + 255) >> 8;
            for (int t = 0; t < nt; t++) tiledesc[tot++] = (e << 8) | t;
        }
        ntiles[0] = tot;
    }
}

// =====================================================================
// 8-phase k-split pipelined 256x256 GEMM template (unchanged from R3).
// LDS: 2 bufs x {A,B} x 2 k-halves x (256 rows x 64B) = 128 KiB.
// vmcnt(8) at odd phases; stage-to-read distance 3 phase-pairs; never
// vmcnt(0) in the main loop. Swizzle: 16B slot ^= (row&3), applied to
// global source (LDS dest linear) and to the ds_read address.
// =====================================================================

#define QOFF(d, ab, kh) ((d)*65536 + (ab)*32768 + (kh)*16384)

#define STAGE(qo, p0, p1, ko)                        \
    do {                                             \
        char* dst_ = lds + (qo) + tid * 16;          \
        gld16((p0) + (ko), dst_);                    \
        gld16((p1) + (ko), dst_ + 8192);             \
    } while (0)

#define RD_A(d, kh, mh)                                                   \
    do {                                                                  \
        const char* Ab_ = lds + QOFF(d, 0, kh) + aOff;                    \
        af[0] = *(const bf16x8*)(Ab_ + ((mh)*4 + 0) * 1024);              \
        af[1] = *(const bf16x8*)(Ab_ + ((mh)*4 + 1) * 1024);              \
        af[2] = *(const bf16x8*)(Ab_ + ((mh)*4 + 2) * 1024);              \
        af[3] = *(const bf16x8*)(Ab_ + ((mh)*4 + 3) * 1024);              \
    } while (0)

#define RD_B(d, kh)                                                       \
    do {                                                                  \
        const char* Bb_ = lds + QOFF(d, 1, kh) + bOff;                    \
        bf[0] = *(const bf16x8*)(Bb_ + 0 * 1024);                         \
        bf[1] = *(const bf16x8*)(Bb_ + 1 * 1024);                         \
        bf[2] = *(const bf16x8*)(Bb_ + 2 * 1024);                         \
        bf[3] = *(const bf16x8*)(Bb_ + 3 * 1024);                         \
    } while (0)

#define MM(mh)                                                            \
    do {                                                                  \
        _Pragma("unroll") for (int m_ = 0; m_ < 4; m_++)                  \
            _Pragma("unroll") for (int n_ = 0; n_ < 4; n_++)              \
                acc[(mh)*4 + m_][n_] = MFMA16(af[m_], bf[n_], acc[(mh)*4 + m_][n_]); \
    } while (0)

#define PHASE_PAIR(dR, khR, qoE, pE0, pE1, koE, qoO, pO0, pO1, koO)       \
    do {                                                                  \
        bf16x8 af[4], bf[4];                                              \
        RD_A(dR, khR, 0);                                                 \
        RD_B(dR, khR);                                                    \
        STAGE(qoE, pE0, pE1, koE);                                        \
        S_BARRIER();                                                      \
        SETPRIO(1); MM(0); SETPRIO(0);                                    \
        S_BARRIER();                                                      \
        RD_A(dR, khR, 1);                                                 \
        STAGE(qoO, pO0, pO1, koO);                                        \
        WAITVM(8);                                                        \
        S_BARRIER();                                                      \
        SETPRIO(1); MM(1); SETPRIO(0);                                    \
        S_BARRIER();                                                      \
    } while (0)

#define PIPE8(NKT)                                                        \
    f32x4 acc[8][4];                                                      \
    _Pragma("unroll") for (int m_ = 0; m_ < 8; m_++)                      \
        _Pragma("unroll") for (int n_ = 0; n_ < 4; n_++) acc[m_][n_] = (f32x4)0.f; \
    int aOff = (wr * 128 + rsel) * 64 + ((g4 ^ (rsel & 3)) << 4);         \
    int bOff = (wc * 64 + rsel) * 64 + ((g4 ^ (rsel & 3)) << 4);          \
    STAGE(QOFF(0, 0, 0), aP0, aP1, 0);                                    \
    STAGE(QOFF(0, 1, 0), bP0, bP1, 0);                                    \
    STAGE(QOFF(0, 0, 1), aP0, aP1, 64);                                   \
    STAGE(QOFF(0, 1, 1), bP0, bP1, 64);                                   \
    STAGE(QOFF(1, 0, 0), aP0, aP1, 128);                                  \
    STAGE(QOFF(1, 1, 0), bP0, bP1, 128);                                  \
    WAITVM(8);                                                            \
    S_BARRIER();                                                          \
    for (int j = 0; j < (NKT) / 2; ++j) {                                 \
        int t1k = (2 * j + 1) * 128 + 64;                                 \
        int t2 = 2 * j + 2; if (t2 >= (NKT)) t2 = 0;                      \
        int t3 = 2 * j + 3; if (t3 >= (NKT)) t3 = 1;                      \
        int t2k0 = t2 * 128, t2k1 = t2 * 128 + 64, t3k0 = t3 * 128;       \
        PHASE_PAIR(0, 0, QOFF(1, 0, 1), aP0, aP1, t1k, QOFF(1, 1, 1), bP0, bP1, t1k);   \
        PHASE_PAIR(0, 1, QOFF(0, 0, 0), aP0, aP1, t2k0, QOFF(0, 1, 0), bP0, bP1, t2k0); \
        PHASE_PAIR(1, 0, QOFF(0, 0, 1), aP0, aP1, t2k1, QOFF(0, 1, 1), bP0, bP1, t2k1); \
        PHASE_PAIR(1, 1, QOFF(1, 0, 0), aP0, aP1, t3k0, QOFF(1, 1, 0), bP0, bP1, t3k0); \
    }                                                                     \
    WAITVM(0);                                                            \
    S_BARRIER();

// ---------------- gate_up GEMM + swiglu -> h ----------------
// grid (72 tile-slots, 16 col-tiles of 128 h-cols); desc-compacted
__global__ __launch_bounds__(512, 2) void gateup8p(const u16* __restrict__ xb, const u16* __restrict__ gub,
                                                   const int* __restrict__ counts,
                                                   const int* __restrict__ ntiles, const int* __restrict__ tiledesc,
                                                   const int* __restrict__ tokslot, u16* __restrict__ h) {
    if ((int)blockIdx.x >= ntiles[0]) return;
    int td = tiledesc[blockIdx.x];
    int e = td >> 8;
    int cnt = counts[e];
    int row0 = (td & 255) * 256;
    int c0 = blockIdx.y * 128;

    extern __shared__ char lds[];
    int tid = threadIdx.x;
    int wv = tid >> 6, ln = tid & 63;
    int wr = wv >> 2, wc = wv & 3;
    int rsel = ln & 15, g4 = ln >> 4;

    // staging sources: thread covers rows (tid>>2) and 128+(tid>>2), slot tid&3
    int srow = tid >> 2, sl = tid & 3;
    int sx = ((sl ^ (srow & 3)) << 4);
    const char* aP0;
    const char* aP1;
    const char* bP0;
    const char* bP1;
    {
        int gr0 = row0 + srow; gr0 = gr0 < cnt ? gr0 : cnt - 1;
        int gr1 = row0 + 128 + srow; gr1 = gr1 < cnt ? gr1 : cnt - 1;
        int t0 = tokslot[e * NTOK + gr0] & 0xFFFF;
        int t1 = tokslot[e * NTOK + gr1] & 0xFFFF;
        aP0 = (const char*)xb + (size_t)t0 * (HID * 2) + sx;
        aP1 = (const char*)xb + (size_t)t1 * (HID * 2) + sx;
        // B row r: group wc=r>>6, wi=r&63; wi<32 -> gate col c0+wc*32+wi, else up
        int r0 = srow, r1 = 128 + srow;
        int wi0 = r0 & 63, wi1 = r1 & 63;
        int b0 = (wi0 >> 5) * 2048 + c0 + (r0 >> 6) * 32 + (wi0 & 31);
        int b1 = (wi1 >> 5) * 2048 + c0 + (r1 >> 6) * 32 + (wi1 & 31);
        bP0 = (const char*)gub + ((size_t)e * 4096 + b0) * (HID * 2) + sx;
        bP1 = (const char*)gub + ((size_t)e * 4096 + b1) * (HID * 2) + sx;
    }

    PIPE8(HID / 64)  // 12 K-tiles

    // epilogue: n in {0,1}=gate, n+2=up; h-col = c0 + wc*32 + n*16 + rsel
#pragma unroll
    for (int mg = 0; mg < 8; mg++) {
#pragma unroll
        for (int j = 0; j < 4; j++) {
            int gr = row0 + wr * 128 + mg * 16 + g4 * 4 + j;
            if (gr >= cnt) continue;
            int ts = tokslot[e * NTOK + gr];
            int tok = ts & 0xFFFF, slot = ts >> 16;
            u16* hrow = h + (size_t)(slot * NTOK + tok) * INTER;
#pragma unroll
            for (int n = 0; n < 2; n++) {
                float gv = acc[mg][n][j];
                float uv = fminf(acc[mg][n + 2][j], 7.0f);
                float sg = gv / (1.0f + __expf(-gv));
                hrow[c0 + wc * 32 + n * 16 + rsel] = f2bf(sg * uv);
            }
        }
    }
}

// ---------------- down GEMM + weighted atomic scatter-add ----------------
// grid (72 tile-slots, 3 col-tiles of 256); desc-compacted
__global__ __launch_bounds__(512, 2) void down8p(const u16* __restrict__ hb, const u16* __restrict__ dnb,
                                                 const int* __restrict__ counts,
                                                 const int* __restrict__ ntiles, const int* __restrict__ tiledesc,
                                                 const int* __restrict__ tokslot,
                                                 const float* __restrict__ wslot, float* __restrict__ out) {
    if ((int)blockIdx.x >= ntiles[0]) return;
    int td = tiledesc[blockIdx.x];
    int e = td >> 8;
    int cnt = counts[e];
    int row0 = (td & 255) * 256;
    int col0 = blockIdx.y * 256;

    extern __shared__ char lds[];
    int tid = threadIdx.x;
    int wv = tid >> 6, ln = tid & 63;
    int wr = wv >> 2, wc = wv & 3;
    int rsel = ln & 15, g4 = ln >> 4;

    int srow = tid >> 2, sl = tid & 3;
    int sx = ((sl ^ (srow & 3)) << 4);
    const char* aP0;
    const char* aP1;
    const char* bP0;
    const char* bP1;
    {
        int gr0 = row0 + srow; gr0 = gr0 < cnt ? gr0 : cnt - 1;
        int gr1 = row0 + 128 + srow; gr1 = gr1 < cnt ? gr1 : cnt - 1;
        int ts0 = tokslot[e * NTOK + gr0];
        int ts1 = tokslot[e * NTOK + gr1];
        aP0 = (const char*)hb + (size_t)((ts0 >> 16) * NTOK + (ts0 & 0xFFFF)) * (INTER * 2) + sx;
        aP1 = (const char*)hb + (size_t)((ts1 >> 16) * NTOK + (ts1 & 0xFFFF)) * (INTER * 2) + sx;
        bP0 = (const char*)dnb + ((size_t)e * HID + col0 + srow) * (INTER * 2) + sx;
        bP1 = (const char*)dnb + ((size_t)e * HID + col0 + 128 + srow) * (INTER * 2) + sx;
    }

    PIPE8(INTER / 64)  // 32 K-tiles

#pragma unroll
    for (int mg = 0; mg < 8; mg++) {
#pragma unroll
        for (int j = 0; j < 4; j++) {
            int gr = row0 + wr * 128 + mg * 16 + g4 * 4 + j;
            if (gr >= cnt) continue;
            int ts = tokslot[e * NTOK + gr];
            int tok = ts & 0xFFFF, slot = ts >> 16;
            float w = wslot[slot * NTOK + tok];
#pragma unroll
            for (int n = 0; n < 4; n++) {
                int col = col0 + wc * 64 + n * 16 + rsel;
                atomicAdd(&out[(size_t)tok * HID + col], w * acc[mg][n][j]);
            }
        }
    }
}

// ---------------- launch ----------------
extern "C" void kernel_launch(void* const* d_in, const int* in_sizes, int n_in,
                              void* d_out, int out_size, void* d_ws, size_t ws_size,
                              hipStream_t stream) {
    const float* x = (const float*)d_in[0];
    const float* rw = (const float*)d_in[1];
    const float* gu = (const float*)d_in[2];
    const float* dn = (const float*)d_in[3];
    float* out = (float*)d_out;
    char* ws = (char*)d_ws;

    // workspace layout (bytes)
    int* counts = (int*)(ws + 0);            // 32
    int* ntiles = (int*)(ws + 64);           // 4
    int* tiledesc = (int*)(ws + 128);        // 72*4 = 288 -> ends 416
    int* tokslot = (int*)(ws + 512);         // 8*8192*4 = 262144 -> ends 262656
    float* wslot = (float*)(ws + 262656);    // 2*8192*4 = 65536 -> ends 328192
    u16* xb = (u16*)(ws + 328192);           // 12,582,912 -> ends 12,911,104
    u16* gub = (u16*)(ws + 12911104);        // 50,331,648 -> ends 63,242,752
    u16* dnb = (u16*)(ws + 63242752);        // 25,165,824 -> ends 88,408,576
    u16* hb = (u16*)(ws + 88408576);         // 67,108,864 -> ends 155,517,440

    zero_kernel<<<1024, 256, 0, stream>>>((float4*)out, NTOK * HID / 4, counts);
    cvt_kernel<<<2048, 256, 0, stream>>>(x, xb, NTOK * HID / 8);
    cvt_kernel<<<2048, 256, 0, stream>>>(gu, gub, NEXP * 2 * INTER * HID / 8);
    cvt_kernel<<<2048, 256, 0, stream>>>(dn, dnb, NEXP * HID * INTER / 8);
    router_kernel<<<NTOK / 4, 256, 0, stream>>>(x, rw, counts, tokslot, wslot);
    sched_kernel<<<1, 64, 0, stream>>>(counts, ntiles, tiledesc);
    gateup8p<<<dim3(72, 16), 512, 131072, stream>>>(xb, gub, counts, ntiles, tiledesc, tokslot, hb);
    down8p<<<dim3(72, 3), 512, 131072, stream>>>(hb, dnb, counts, ntiles, tiledesc, tokslot, wslot, out);
}

// Round 5
// 332.281 us; speedup vs baseline: 2.8492x; 1.4961x over previous
//
#include <hip/hip_runtime.h>
#include <hip/hip_bf16.h>

typedef unsigned short u16;
typedef unsigned int u32;
typedef short bf16x8 __attribute__((ext_vector_type(8)));
typedef float f32x4 __attribute__((ext_vector_type(4)));

#define NTOK 8192
#define HID 768
#define INTER 2048
#define NEXP 8

#define MFMA16(a, b, c) __builtin_amdgcn_mfma_f32_16x16x32_bf16(a, b, c, 0, 0, 0)
#define S_BARRIER() __builtin_amdgcn_s_barrier()
#define SETPRIO(x) __builtin_amdgcn_s_setprio(x)
#define WAITVM(n) asm volatile("s_waitcnt vmcnt(" #n ")" ::: "memory")

__device__ __forceinline__ u16 f2bf(float f) {
    u32 u = __builtin_bit_cast(u32, f);
    u32 r = (u + 0x7FFFu + ((u >> 16) & 1u)) >> 16;
    return (u16)r;
}

__device__ __forceinline__ void gld16(const void* g, void* l) {
    __builtin_amdgcn_global_load_lds((const __attribute__((address_space(1))) void*)g,
                                     (__attribute__((address_space(3))) void*)l, 16, 0, 0);
}

// ---------------- zero out ----------------
__global__ __launch_bounds__(256) void zero_kernel(float4* out4, int n4) {
    int i = blockIdx.x * blockDim.x + threadIdx.x;
    float4 z = {0.f, 0.f, 0.f, 0.f};
    int stride = gridDim.x * blockDim.x;
    for (int k = i; k < n4; k += stride) out4[k] = z;
}

// ---------------- fp32 -> bf16 convert ----------------
__global__ __launch_bounds__(256) void cvt_kernel(const float* __restrict__ src, u16* __restrict__ dst, int n8) {
    int i = blockIdx.x * blockDim.x + threadIdx.x;
    int stride = gridDim.x * blockDim.x;
    for (; i < n8; i += stride) {
        const float4* s = (const float4*)(src + (size_t)i * 8);
        float4 a = s[0], b = s[1];
        u16 r[8] = {f2bf(a.x), f2bf(a.y), f2bf(a.z), f2bf(a.w),
                    f2bf(b.x), f2bf(b.y), f2bf(b.z), f2bf(b.w)};
        *(uint4*)(dst + (size_t)i * 8) = *(const uint4*)r;
    }
}

// ---------------- router: logits, top-2, softmax -> route+weights (NO atomics) ----------------
__global__ __launch_bounds__(256) void router2(const float* __restrict__ x, const float* __restrict__ rw,
                                               u32* __restrict__ route, float* __restrict__ wslot) {
    int wv = threadIdx.x >> 6, ln = threadIdx.x & 63;
    int t = blockIdx.x * 4 + wv;
    if (t >= NTOK) return;
    float xr[12];
#pragma unroll
    for (int j = 0; j < 12; j++) xr[j] = x[(size_t)t * HID + ln + j * 64];
    float lg[NEXP];
#pragma unroll
    for (int e = 0; e < NEXP; e++) {
        float a = 0.f;
#pragma unroll
        for (int j = 0; j < 12; j++) a += xr[j] * rw[e * HID + ln + j * 64];
#pragma unroll
        for (int off = 32; off; off >>= 1) a += __shfl_xor(a, off);
        lg[e] = a;
    }
    int i0 = 0;
    float v0 = lg[0];
#pragma unroll
    for (int e = 1; e < NEXP; e++)
        if (lg[e] > v0) { v0 = lg[e]; i0 = e; }
    int i1 = -1;
    float v1 = -1e30f;
#pragma unroll
    for (int e = 0; e < NEXP; e++) {
        if (e == i0) continue;
        if (lg[e] > v1) { v1 = lg[e]; i1 = e; }
    }
    float w0 = 1.f / (1.f + __expf(v1 - v0));
    float w1 = 1.f - w0;
    if (ln == 0) {
        wslot[0 * NTOK + t] = w0;
        wslot[1 * NTOK + t] = w1;
        route[t] = (u32)i0 | ((u32)i1 << 8);
    }
}

// ---------------- scatter: deterministic counting sort + fused schedule ----------------
// 1 block x 1024 threads; thread owns tokens [tid*8, tid*8+8)
__global__ __launch_bounds__(1024) void scatter_kernel(const u32* __restrict__ route, int* __restrict__ counts,
                                                       int* __restrict__ tokslot, int* __restrict__ ntiles,
                                                       int* __restrict__ tiledesc) {
    __shared__ int sc[NEXP][1024];
    int tid = threadIdx.x;
    u32 rt[8];
    int cnt[NEXP] = {0, 0, 0, 0, 0, 0, 0, 0};
#pragma unroll
    for (int k = 0; k < 8; k++) {
        rt[k] = route[tid * 8 + k];
        cnt[rt[k] & 255]++;
        cnt[(rt[k] >> 8) & 255]++;
    }
#pragma unroll
    for (int e = 0; e < NEXP; e++) sc[e][tid] = cnt[e];
    __syncthreads();
    for (int off = 1; off < 1024; off <<= 1) {
        int v[NEXP];
#pragma unroll
        for (int e = 0; e < NEXP; e++) v[e] = (tid >= off) ? sc[e][tid - off] : 0;
        __syncthreads();
#pragma unroll
        for (int e = 0; e < NEXP; e++)
            if (tid >= off) sc[e][tid] += v[e];
        __syncthreads();
    }
    int base[NEXP];
#pragma unroll
    for (int e = 0; e < NEXP; e++) base[e] = sc[e][tid] - cnt[e];
#pragma unroll
    for (int k = 0; k < 8; k++) {
        int t = tid * 8 + k;
        int e0 = rt[k] & 255, e1 = (rt[k] >> 8) & 255;
        tokslot[e0 * NTOK + base[e0]] = t;
        base[e0]++;
        tokslot[e1 * NTOK + base[e1]] = t | (1 << 16);
        base[e1]++;
    }
    if (tid == 0) {
        int tot = 0;
        for (int e = 0; e < NEXP; e++) {
            int c = sc[e][1023];
            counts[e] = c;
            int nt = (c + 255) >> 8;
            for (int q = 0; q < nt; q++) tiledesc[tot++] = (e << 8) | q;
        }
        ntiles[0] = tot;
    }
}

// =====================================================================
// 8-phase k-split pipelined 256x256 GEMM template (unchanged).
// LDS: 2 bufs x {A,B} x 2 k-halves x (256 rows x 64B) = 128 KiB.
// vmcnt(8) at odd phases; never vmcnt(0) in the main loop. Swizzle:
// 16B slot ^= (row&3) on global source (LDS dest linear) and ds_read.
// =====================================================================

#define QOFF(d, ab, kh) ((d)*65536 + (ab)*32768 + (kh)*16384)

#define STAGE(qo, p0, p1, ko)                        \
    do {                                             \
        char* dst_ = lds + (qo) + tid * 16;          \
        gld16((p0) + (ko), dst_);                    \
        gld16((p1) + (ko), dst_ + 8192);             \
    } while (0)

#define RD_A(d, kh, mh)                                                   \
    do {                                                                  \
        const char* Ab_ = lds + QOFF(d, 0, kh) + aOff;                    \
        af[0] = *(const bf16x8*)(Ab_ + ((mh)*4 + 0) * 1024);              \
        af[1] = *(const bf16x8*)(Ab_ + ((mh)*4 + 1) * 1024);              \
        af[2] = *(const bf16x8*)(Ab_ + ((mh)*4 + 2) * 1024);              \
        af[3] = *(const bf16x8*)(Ab_ + ((mh)*4 + 3) * 1024);              \
    } while (0)

#define RD_B(d, kh)                                                       \
    do {                                                                  \
        const char* Bb_ = lds + QOFF(d, 1, kh) + bOff;                    \
        bf[0] = *(const bf16x8*)(Bb_ + 0 * 1024);                         \
        bf[1] = *(const bf16x8*)(Bb_ + 1 * 1024);                         \
        bf[2] = *(const bf16x8*)(Bb_ + 2 * 1024);                         \
        bf[3] = *(const bf16x8*)(Bb_ + 3 * 1024);                         \
    } while (0)

#define MM(mh)                                                            \
    do {                                                                  \
        _Pragma("unroll") for (int m_ = 0; m_ < 4; m_++)                  \
            _Pragma("unroll") for (int n_ = 0; n_ < 4; n_++)              \
                acc[(mh)*4 + m_][n_] = MFMA16(af[m_], bf[n_], acc[(mh)*4 + m_][n_]); \
    } while (0)

#define PHASE_PAIR(dR, khR, qoE, pE0, pE1, koE, qoO, pO0, pO1, koO)       \
    do {                                                                  \
        bf16x8 af[4], bf[4];                                              \
        RD_A(dR, khR, 0);                                                 \
        RD_B(dR, khR);                                                    \
        STAGE(qoE, pE0, pE1, koE);                                        \
        S_BARRIER();                                                      \
        SETPRIO(1); MM(0); SETPRIO(0);                                    \
        S_BARRIER();                                                      \
        RD_A(dR, khR, 1);                                                 \
        STAGE(qoO, pO0, pO1, koO);                                        \
        WAITVM(8);                                                        \
        S_BARRIER();                                                      \
        SETPRIO(1); MM(1); SETPRIO(0);                                    \
        S_BARRIER();                                                      \
    } while (0)

#define PIPE8(NKT)                                                        \
    f32x4 acc[8][4];                                                      \
    _Pragma("unroll") for (int m_ = 0; m_ < 8; m_++)                      \
        _Pragma("unroll") for (int n_ = 0; n_ < 4; n_++) acc[m_][n_] = (f32x4)0.f; \
    int aOff = (wr * 128 + rsel) * 64 + ((g4 ^ (rsel & 3)) << 4);         \
    int bOff = (wc * 64 + rsel) * 64 + ((g4 ^ (rsel & 3)) << 4);          \
    STAGE(QOFF(0, 0, 0), aP0, aP1, 0);                                    \
    STAGE(QOFF(0, 1, 0), bP0, bP1, 0);                                    \
    STAGE(QOFF(0, 0, 1), aP0, aP1, 64);                                   \
    STAGE(QOFF(0, 1, 1), bP0, bP1, 64);                                   \
    STAGE(QOFF(1, 0, 0), aP0, aP1, 128);                                  \
    STAGE(QOFF(1, 1, 0), bP0, bP1, 128);                                  \
    WAITVM(8);                                                            \
    S_BARRIER();                                                          \
    for (int j = 0; j < (NKT) / 2; ++j) {                                 \
        int t1k = (2 * j + 1) * 128 + 64;                                 \
        int t2 = 2 * j + 2; if (t2 >= (NKT)) t2 = 0;                      \
        int t3 = 2 * j + 3; if (t3 >= (NKT)) t3 = 1;                      \
        int t2k0 = t2 * 128, t2k1 = t2 * 128 + 64, t3k0 = t3 * 128;       \
        PHASE_PAIR(0, 0, QOFF(1, 0, 1), aP0, aP1, t1k, QOFF(1, 1, 1), bP0, bP1, t1k);   \
        PHASE_PAIR(0, 1, QOFF(0, 0, 0), aP0, aP1, t2k0, QOFF(0, 1, 0), bP0, bP1, t2k0); \
        PHASE_PAIR(1, 0, QOFF(0, 0, 1), aP0, aP1, t2k1, QOFF(0, 1, 1), bP0, bP1, t2k1); \
        PHASE_PAIR(1, 1, QOFF(1, 0, 0), aP0, aP1, t3k0, QOFF(1, 1, 0), bP0, bP1, t3k0); \
    }                                                                     \
    WAITVM(0);                                                            \
    S_BARRIER();

// ---------------- gate_up GEMM + swiglu -> h ----------------
// grid (72 tile-slots, 16 col-tiles of 128 h-cols); desc-compacted
__global__ __launch_bounds__(512, 2) void gateup8p(const u16* __restrict__ xb, const u16* __restrict__ gub,
                                                   const int* __restrict__ counts,
                                                   const int* __restrict__ ntiles, const int* __restrict__ tiledesc,
                                                   const int* __restrict__ tokslot, u16* __restrict__ h) {
    if ((int)blockIdx.x >= ntiles[0]) return;
    int td = tiledesc[blockIdx.x];
    int e = td >> 8;
    int cnt = counts[e];
    int row0 = (td & 255) * 256;
    int c0 = blockIdx.y * 128;

    extern __shared__ char lds[];
    int tid = threadIdx.x;
    int wv = tid >> 6, ln = tid & 63;
    int wr = wv >> 2, wc = wv & 3;
    int rsel = ln & 15, g4 = ln >> 4;

    int srow = tid >> 2, sl = tid & 3;
    int sx = ((sl ^ (srow & 3)) << 4);
    const char* aP0;
    const char* aP1;
    const char* bP0;
    const char* bP1;
    {
        int gr0 = row0 + srow; gr0 = gr0 < cnt ? gr0 : cnt - 1;
        int gr1 = row0 + 128 + srow; gr1 = gr1 < cnt ? gr1 : cnt - 1;
        int t0 = tokslot[e * NTOK + gr0] & 0xFFFF;
        int t1 = tokslot[e * NTOK + gr1] & 0xFFFF;
        aP0 = (const char*)xb + (size_t)t0 * (HID * 2) + sx;
        aP1 = (const char*)xb + (size_t)t1 * (HID * 2) + sx;
        int r0 = srow, r1 = 128 + srow;
        int wi0 = r0 & 63, wi1 = r1 & 63;
        int b0 = (wi0 >> 5) * 2048 + c0 + (r0 >> 6) * 32 + (wi0 & 31);
        int b1 = (wi1 >> 5) * 2048 + c0 + (r1 >> 6) * 32 + (wi1 & 31);
        bP0 = (const char*)gub + ((size_t)e * 4096 + b0) * (HID * 2) + sx;
        bP1 = (const char*)gub + ((size_t)e * 4096 + b1) * (HID * 2) + sx;
    }

    PIPE8(HID / 64)  // 12 K-tiles

#pragma unroll
    for (int mg = 0; mg < 8; mg++) {
#pragma unroll
        for (int j = 0; j < 4; j++) {
            int gr = row0 + wr * 128 + mg * 16 + g4 * 4 + j;
            if (gr >= cnt) continue;
            int ts = tokslot[e * NTOK + gr];
            int tok = ts & 0xFFFF, slot = ts >> 16;
            u16* hrow = h + (size_t)(slot * NTOK + tok) * INTER;
#pragma unroll
            for (int n = 0; n < 2; n++) {
                float gv = acc[mg][n][j];
                float uv = fminf(acc[mg][n + 2][j], 7.0f);
                float sg = gv / (1.0f + __expf(-gv));
                hrow[c0 + wc * 32 + n * 16 + rsel] = f2bf(sg * uv);
            }
        }
    }
}

// ---------------- down GEMM + weighted atomic scatter-add ----------------
// grid (72 tile-slots, 3 col-tiles of 256); desc-compacted
__global__ __launch_bounds__(512, 2) void down8p(const u16* __restrict__ hb, const u16* __restrict__ dnb,
                                                 const int* __restrict__ counts,
                                                 const int* __restrict__ ntiles, const int* __restrict__ tiledesc,
                                                 const int* __restrict__ tokslot,
                                                 const float* __restrict__ wslot, float* __restrict__ out) {
    if ((int)blockIdx.x >= ntiles[0]) return;
    int td = tiledesc[blockIdx.x];
    int e = td >> 8;
    int cnt = counts[e];
    int row0 = (td & 255) * 256;
    int col0 = blockIdx.y * 256;

    extern __shared__ char lds[];
    int tid = threadIdx.x;
    int wv = tid >> 6, ln = tid & 63;
    int wr = wv >> 2, wc = wv & 3;
    int rsel = ln & 15, g4 = ln >> 4;

    int srow = tid >> 2, sl = tid & 3;
    int sx = ((sl ^ (srow & 3)) << 4);
    const char* aP0;
    const char* aP1;
    const char* bP0;
    const char* bP1;
    {
        int gr0 = row0 + srow; gr0 = gr0 < cnt ? gr0 : cnt - 1;
        int gr1 = row0 + 128 + srow; gr1 = gr1 < cnt ? gr1 : cnt - 1;
        int ts0 = tokslot[e * NTOK + gr0];
        int ts1 = tokslot[e * NTOK + gr1];
        aP0 = (const char*)hb + (size_t)((ts0 >> 16) * NTOK + (ts0 & 0xFFFF)) * (INTER * 2) + sx;
        aP1 = (const char*)hb + (size_t)((ts1 >> 16) * NTOK + (ts1 & 0xFFFF)) * (INTER * 2) + sx;
        bP0 = (const char*)dnb + ((size_t)e * HID + col0 + srow) * (INTER * 2) + sx;
        bP1 = (const char*)dnb + ((size_t)e * HID + col0 + 128 + srow) * (INTER * 2) + sx;
    }

    PIPE8(INTER / 64)  // 32 K-tiles

#pragma unroll
    for (int mg = 0; mg < 8; mg++) {
#pragma unroll
        for (int j = 0; j < 4; j++) {
            int gr = row0 + wr * 128 + mg * 16 + g4 * 4 + j;
            if (gr >= cnt) continue;
            int ts = tokslot[e * NTOK + gr];
            int tok = ts & 0xFFFF, slot = ts >> 16;
            float w = wslot[slot * NTOK + tok];
#pragma unroll
            for (int n = 0; n < 4; n++) {
                int col = col0 + wc * 64 + n * 16 + rsel;
                atomicAdd(&out[(size_t)tok * HID + col], w * acc[mg][n][j]);
            }
        }
    }
}

// ---------------- launch ----------------
extern "C" void kernel_launch(void* const* d_in, const int* in_sizes, int n_in,
                              void* d_out, int out_size, void* d_ws, size_t ws_size,
                              hipStream_t stream) {
    const float* x = (const float*)d_in[0];
    const float* rw = (const float*)d_in[1];
    const float* gu = (const float*)d_in[2];
    const float* dn = (const float*)d_in[3];
    float* out = (float*)d_out;
    char* ws = (char*)d_ws;

    // workspace layout (bytes)
    int* counts = (int*)(ws + 0);            // 32
    int* ntiles = (int*)(ws + 64);           // 4
    int* tiledesc = (int*)(ws + 128);        // 72*4 = 288 -> ends 416
    int* tokslot = (int*)(ws + 512);         // 8*8192*4 = 262144 -> ends 262656
    float* wslot = (float*)(ws + 262656);    // 2*8192*4 = 65536 -> ends 328192
    u16* xb = (u16*)(ws + 328192);           // 12,582,912 -> ends 12,911,104
    u16* gub = (u16*)(ws + 12911104);        // 50,331,648 -> ends 63,242,752
    u16* dnb = (u16*)(ws + 63242752);        // 25,165,824 -> ends 88,408,576
    u16* hb = (u16*)(ws + 88408576);         // 67,108,864 -> ends 155,517,440
    // route aliases the head of hb: written by router2, consumed by scatter,
    // then hb is (re)written by gateup8p strictly afterwards on the stream.
    u32* route = (u32*)(ws + 88408576);      // 8192*4 = 32768

    zero_kernel<<<1024, 256, 0, stream>>>((float4*)out, NTOK * HID / 4);
    cvt_kernel<<<2048, 256, 0, stream>>>(x, xb, NTOK * HID / 8);
    cvt_kernel<<<2048, 256, 0, stream>>>(gu, gub, NEXP * 2 * INTER * HID / 8);
    cvt_kernel<<<2048, 256, 0, stream>>>(dn, dnb, NEXP * HID * INTER / 8);
    router2<<<NTOK / 4, 256, 0, stream>>>(x, rw, route, wslot);
    scatter_kernel<<<1, 1024, 0, stream>>>(route, counts, tokslot, ntiles, tiledesc);
    gateup8p<<<dim3(72, 16), 512, 131072, stream>>>(xb, gub, counts, ntiles, tiledesc, tokslot, hb);
    down8p<<<dim3(72, 3), 512, 131072, stream>>>(hb, dnb, counts, ntiles, tiledesc, tokslot, wslot, out);
}

// Round 6
// 315.392 us; speedup vs baseline: 3.0018x; 1.0535x over previous
//
#include <hip/hip_runtime.h>
#include <hip/hip_bf16.h>

typedef unsigned short u16;
typedef unsigned int u32;
typedef short bf16x8 __attribute__((ext_vector_type(8)));
typedef float f32x4 __attribute__((ext_vector_type(4)));

#define NTOK 8192
#define HID 768
#define INTER 2048
#define NEXP 8

#define MFMA16(a, b, c) __builtin_amdgcn_mfma_f32_16x16x32_bf16(a, b, c, 0, 0, 0)
#define S_BARRIER() __builtin_amdgcn_s_barrier()
#define SETPRIO(x) __builtin_amdgcn_s_setprio(x)
#define WAITVM(n) asm volatile("s_waitcnt vmcnt(" #n ")" ::: "memory")

__device__ __forceinline__ u16 f2bf(float f) {
    u32 u = __builtin_bit_cast(u32, f);
    u32 r = (u + 0x7FFFu + ((u >> 16) & 1u)) >> 16;
    return (u16)r;
}

__device__ __forceinline__ void gld16(const void* g, void* l) {
    __builtin_amdgcn_global_load_lds((const __attribute__((address_space(1))) void*)g,
                                     (__attribute__((address_space(3))) void*)l, 16, 0, 0);
}

// ---------------- zero out ----------------
__global__ __launch_bounds__(256) void zero_kernel(float4* out4, int n4) {
    int i = blockIdx.x * blockDim.x + threadIdx.x;
    float4 z = {0.f, 0.f, 0.f, 0.f};
    int stride = gridDim.x * blockDim.x;
    for (int k = i; k < n4; k += stride) out4[k] = z;
}

// ---------------- fp32 -> bf16 convert ----------------
__global__ __launch_bounds__(256) void cvt_kernel(const float* __restrict__ src, u16* __restrict__ dst, int n8) {
    int i = blockIdx.x * blockDim.x + threadIdx.x;
    int stride = gridDim.x * blockDim.x;
    for (; i < n8; i += stride) {
        const float4* s = (const float4*)(src + (size_t)i * 8);
        float4 a = s[0], b = s[1];
        u16 r[8] = {f2bf(a.x), f2bf(a.y), f2bf(a.z), f2bf(a.w),
                    f2bf(b.x), f2bf(b.y), f2bf(b.z), f2bf(b.w)};
        *(uint4*)(dst + (size_t)i * 8) = *(const uint4*)r;
    }
}

// ---------------- router: logits, top-2, softmax (NO atomics) ----------------
__global__ __launch_bounds__(256) void router2(const float* __restrict__ x, const float* __restrict__ rw,
                                               u32* __restrict__ route, float* __restrict__ wslot) {
    int wv = threadIdx.x >> 6, ln = threadIdx.x & 63;
    int t = blockIdx.x * 4 + wv;
    if (t >= NTOK) return;
    float xr[12];
#pragma unroll
    for (int j = 0; j < 12; j++) xr[j] = x[(size_t)t * HID + ln + j * 64];
    float lg[NEXP];
#pragma unroll
    for (int e = 0; e < NEXP; e++) {
        float a = 0.f;
#pragma unroll
        for (int j = 0; j < 12; j++) a += xr[j] * rw[e * HID + ln + j * 64];
#pragma unroll
        for (int off = 32; off; off >>= 1) a += __shfl_xor(a, off);
        lg[e] = a;
    }
    int i0 = 0;
    float v0 = lg[0];
#pragma unroll
    for (int e = 1; e < NEXP; e++)
        if (lg[e] > v0) { v0 = lg[e]; i0 = e; }
    int i1 = -1;
    float v1 = -1e30f;
#pragma unroll
    for (int e = 0; e < NEXP; e++) {
        if (e == i0) continue;
        if (lg[e] > v1) { v1 = lg[e]; i1 = e; }
    }
    float w0 = 1.f / (1.f + __expf(v1 - v0));
    float w1 = 1.f - w0;
    if (ln == 0) {
        wslot[0 * NTOK + t] = w0;
        wslot[1 * NTOK + t] = w1;
        route[t] = (u32)i0 | ((u32)i1 << 8);
    }
}

// ---------------- scatter: deterministic counting sort + fused schedule ----------------
__global__ __launch_bounds__(1024) void scatter_kernel(const u32* __restrict__ route, int* __restrict__ counts,
                                                       int* __restrict__ tokslot, int* __restrict__ ntiles,
                                                       int* __restrict__ tiledesc) {
    __shared__ int sc[NEXP][1024];
    int tid = threadIdx.x;
    u32 rt[8];
    int cnt[NEXP] = {0, 0, 0, 0, 0, 0, 0, 0};
#pragma unroll
    for (int k = 0; k < 8; k++) {
        rt[k] = route[tid * 8 + k];
        cnt[rt[k] & 255]++;
        cnt[(rt[k] >> 8) & 255]++;
    }
#pragma unroll
    for (int e = 0; e < NEXP; e++) sc[e][tid] = cnt[e];
    __syncthreads();
    for (int off = 1; off < 1024; off <<= 1) {
        int v[NEXP];
#pragma unroll
        for (int e = 0; e < NEXP; e++) v[e] = (tid >= off) ? sc[e][tid - off] : 0;
        __syncthreads();
#pragma unroll
        for (int e = 0; e < NEXP; e++)
            if (tid >= off) sc[e][tid] += v[e];
        __syncthreads();
    }
    int base[NEXP];
#pragma unroll
    for (int e = 0; e < NEXP; e++) base[e] = sc[e][tid] - cnt[e];
#pragma unroll
    for (int k = 0; k < 8; k++) {
        int t = tid * 8 + k;
        int e0 = rt[k] & 255, e1 = (rt[k] >> 8) & 255;
        tokslot[e0 * NTOK + base[e0]] = t;
        base[e0]++;
        tokslot[e1 * NTOK + base[e1]] = t | (1 << 16);
        base[e1]++;
    }
    if (tid == 0) {
        int tot = 0;
        for (int e = 0; e < NEXP; e++) {
            int c = sc[e][1023];
            counts[e] = c;
            int nt = (c + 255) >> 8;
            for (int q = 0; q < nt; q++) tiledesc[tot++] = (e << 8) | q;
        }
        ntiles[0] = tot;
    }
}

// =====================================================================
// 2-phase double-buffered 256x256 GEMM, BK=64 (128B rows).
// LDS: 2 bufs x (A 32KB + B 32KB) = 128 KiB.
// Per K-tile: STAGE(next buf); read frags ks0; 32 MFMA; read ks1;
// 32 MFMA; vmcnt(0); s_barrier.   ONE barrier + ONE vmcnt per tile.
// Liveness: stage at top of iter t writes buf[(t+1)&1], last READ at
// iter t-1; those reads retire before t-1's MFMA (compiler lgkmcnt)
// which precedes the end-of-(t-1) barrier -> race-free. vmcnt(0)+
// barrier at end of t orders stage writes before reads at t+1.
// Swizzle (128B rows = full bank stripe): 16B-slot ^= (row&7), applied
// to the GLOBAL source (LDS dest linear, involution) and to the
// ds_read offset -> every 16-lane phase is 2-way (free, m136).
// =====================================================================

#define STAGE8(d, kt)                                        \
    do {                                                     \
        char* dA_ = lds + (d)*65536 + tid * 16;              \
        char* dB_ = dA_ + 32768;                             \
        size_t ko_ = (size_t)(kt)*128;                       \
        gld16(aP[0] + ko_, dA_);                             \
        gld16(aP[1] + ko_, dA_ + 8192);                      \
        gld16(aP[2] + ko_, dA_ + 16384);                     \
        gld16(aP[3] + ko_, dA_ + 24576);                     \
        gld16(bP[0] + ko_, dB_);                             \
        gld16(bP[1] + ko_, dB_ + 8192);                      \
        gld16(bP[2] + ko_, dB_ + 16384);                     \
        gld16(bP[3] + ko_, dB_ + 24576);                     \
    } while (0)

#define MMALL()                                                           \
    do {                                                                  \
        _Pragma("unroll") for (int m_ = 0; m_ < 8; m_++)                  \
            _Pragma("unroll") for (int n_ = 0; n_ < 4; n_++)              \
                acc[m_][n_] = MFMA16(af[m_], bfr[n_], acc[m_][n_]);       \
    } while (0)

#define PIPE2(NKT)                                                        \
    f32x4 acc[8][4];                                                      \
    _Pragma("unroll") for (int m_ = 0; m_ < 8; m_++)                      \
        _Pragma("unroll") for (int n_ = 0; n_ < 4; n_++) acc[m_][n_] = (f32x4)0.f; \
    const int aBase = (wr * 128 + rsel) * 128;                            \
    const int bBase = 32768 + (wc * 64 + rsel) * 128;                     \
    const int s0 = ((g4 ^ (rsel & 7)) << 4);                              \
    const int s1 = (((4 + g4) ^ (rsel & 7)) << 4);                        \
    STAGE8(0, 0);                                                         \
    WAITVM(0);                                                            \
    S_BARRIER();                                                          \
    for (int t = 0; t < (NKT); ++t) {                                     \
        if (t + 1 < (NKT)) STAGE8((t + 1) & 1, t + 1);                    \
        const char* Tb = lds + (t & 1) * 65536;                           \
        bf16x8 af[8], bfr[4];                                             \
        _Pragma("unroll") for (int m_ = 0; m_ < 8; m_++)                  \
            af[m_] = *(const bf16x8*)(Tb + aBase + m_ * 2048 + s0);       \
        _Pragma("unroll") for (int n_ = 0; n_ < 4; n_++)                  \
            bfr[n_] = *(const bf16x8*)(Tb + bBase + n_ * 2048 + s0);      \
        SETPRIO(1); MMALL(); SETPRIO(0);                                  \
        _Pragma("unroll") for (int m_ = 0; m_ < 8; m_++)                  \
            af[m_] = *(const bf16x8*)(Tb + aBase + m_ * 2048 + s1);       \
        _Pragma("unroll") for (int n_ = 0; n_ < 4; n_++)                  \
            bfr[n_] = *(const bf16x8*)(Tb + bBase + n_ * 2048 + s1);      \
        SETPRIO(1); MMALL(); SETPRIO(0);                                  \
        WAITVM(0);                                                        \
        S_BARRIER();                                                      \
    }

// ---------------- gate_up GEMM + swiglu -> h ----------------
// grid (72 tile-slots, 16 col-tiles of 128 h-cols); desc-compacted
__global__ __launch_bounds__(512, 2) void gateup2p(const u16* __restrict__ xb, const u16* __restrict__ gub,
                                                   const int* __restrict__ counts,
                                                   const int* __restrict__ ntiles, const int* __restrict__ tiledesc,
                                                   const int* __restrict__ tokslot, u16* __restrict__ h) {
    if ((int)blockIdx.x >= ntiles[0]) return;
    int td = tiledesc[blockIdx.x];
    int e = td >> 8;
    int cnt = counts[e];
    int row0 = (td & 255) * 256;
    int c0 = blockIdx.y * 128;

    extern __shared__ char lds[];
    int tid = threadIdx.x;
    int wv = tid >> 6, ln = tid & 63;
    int wr = wv >> 2, wc = wv & 3;
    int rsel = ln & 15, g4 = ln >> 4;

    // staging: thread covers rows c*64 + (tid>>3), 16B-slot tid&7 (c=0..3)
    int srow = tid >> 3;
    int sswz = ((tid & 7) ^ (srow & 7)) << 4;
    const char* aP[4];
    const char* bP[4];
#pragma unroll
    for (int c = 0; c < 4; c++) {
        int r = c * 64 + srow;
        int gr = row0 + r;
        gr = gr < cnt ? gr : cnt - 1;
        int tok = tokslot[e * NTOK + gr] & 0xFFFF;
        aP[c] = (const char*)xb + (size_t)tok * (HID * 2) + sswz;
        // B row r: group wc=r>>6, wi=r&63; wi<32 -> gate col, else up col
        int wi = r & 63;
        int b = (wi >> 5) * 2048 + c0 + (r >> 6) * 32 + (wi & 31);
        bP[c] = (const char*)gub + ((size_t)e * 4096 + b) * (HID * 2) + sswz;
    }

    PIPE2(HID / 64)  // 12 K-tiles

    // epilogue: n in {0,1}=gate, n+2=up; h-col = c0 + wc*32 + n*16 + rsel
#pragma unroll
    for (int mg = 0; mg < 8; mg++) {
#pragma unroll
        for (int j = 0; j < 4; j++) {
            int gr = row0 + wr * 128 + mg * 16 + g4 * 4 + j;
            if (gr >= cnt) continue;
            int ts = tokslot[e * NTOK + gr];
            int tok = ts & 0xFFFF, slot = ts >> 16;
            u16* hrow = h + (size_t)(slot * NTOK + tok) * INTER;
#pragma unroll
            for (int n = 0; n < 2; n++) {
                float gv = acc[mg][n][j];
                float uv = fminf(acc[mg][n + 2][j], 7.0f);
                float sg = gv / (1.0f + __expf(-gv));
                hrow[c0 + wc * 32 + n * 16 + rsel] = f2bf(sg * uv);
            }
        }
    }
}

// ---------------- down GEMM + weighted atomic scatter-add ----------------
// grid (72 tile-slots, 3 col-tiles of 256); desc-compacted
__global__ __launch_bounds__(512, 2) void down2p(const u16* __restrict__ hb, const u16* __restrict__ dnb,
                                                 const int* __restrict__ counts,
                                                 const int* __restrict__ ntiles, const int* __restrict__ tiledesc,
                                                 const int* __restrict__ tokslot,
                                                 const float* __restrict__ wslot, float* __restrict__ out) {
    if ((int)blockIdx.x >= ntiles[0]) return;
    int td = tiledesc[blockIdx.x];
    int e = td >> 8;
    int cnt = counts[e];
    int row0 = (td & 255) * 256;
    int col0 = blockIdx.y * 256;

    extern __shared__ char lds[];
    int tid = threadIdx.x;
    int wv = tid >> 6, ln = tid & 63;
    int wr = wv >> 2, wc = wv & 3;
    int rsel = ln & 15, g4 = ln >> 4;

    int srow = tid >> 3;
    int sswz = ((tid & 7) ^ (srow & 7)) << 4;
    const char* aP[4];
    const char* bP[4];
#pragma unroll
    for (int c = 0; c < 4; c++) {
        int r = c * 64 + srow;
        int gr = row0 + r;
        gr = gr < cnt ? gr : cnt - 1;
        int ts = tokslot[e * NTOK + gr];
        aP[c] = (const char*)hb + (size_t)((ts >> 16) * NTOK + (ts & 0xFFFF)) * (INTER * 2) + sswz;
        bP[c] = (const char*)dnb + ((size_t)e * HID + col0 + r) * (INTER * 2) + sswz;
    }

    PIPE2(INTER / 64)  // 32 K-tiles

#pragma unroll
    for (int mg = 0; mg < 8; mg++) {
#pragma unroll
        for (int j = 0; j < 4; j++) {
            int gr = row0 + wr * 128 + mg * 16 + g4 * 4 + j;
            if (gr >= cnt) continue;
            int ts = tokslot[e * NTOK + gr];
            int tok = ts & 0xFFFF, slot = ts >> 16;
            float w = wslot[slot * NTOK + tok];
#pragma unroll
            for (int n = 0; n < 4; n++) {
                int col = col0 + wc * 64 + n * 16 + rsel;
                atomicAdd(&out[(size_t)tok * HID + col], w * acc[mg][n][j]);
            }
        }
    }
}

// ---------------- launch ----------------
extern "C" void kernel_launch(void* const* d_in, const int* in_sizes, int n_in,
                              void* d_out, int out_size, void* d_ws, size_t ws_size,
                              hipStream_t stream) {
    const float* x = (const float*)d_in[0];
    const float* rw = (const float*)d_in[1];
    const float* gu = (const float*)d_in[2];
    const float* dn = (const float*)d_in[3];
    float* out = (float*)d_out;
    char* ws = (char*)d_ws;

    // workspace layout (bytes)
    int* counts = (int*)(ws + 0);            // 32
    int* ntiles = (int*)(ws + 64);           // 4
    int* tiledesc = (int*)(ws + 128);        // 72*4 -> ends 416
    int* tokslot = (int*)(ws + 512);         // 8*8192*4 -> ends 262656
    float* wslot = (float*)(ws + 262656);    // 2*8192*4 -> ends 328192
    u16* xb = (u16*)(ws + 328192);           // 12,582,912 -> ends 12,911,104
    u16* gub = (u16*)(ws + 12911104);        // 50,331,648 -> ends 63,242,752
    u16* dnb = (u16*)(ws + 63242752);        // 25,165,824 -> ends 88,408,576
    u16* hb = (u16*)(ws + 88408576);         // 67,108,864 -> ends 155,517,440
    // route aliases the head of hb: written by router2, consumed by scatter,
    // then hb is (re)written by gateup2p strictly afterwards on the stream.
    u32* route = (u32*)(ws + 88408576);      // 8192*4

    zero_kernel<<<1024, 256, 0, stream>>>((float4*)out, NTOK * HID / 4);
    cvt_kernel<<<2048, 256, 0, stream>>>(x, xb, NTOK * HID / 8);
    cvt_kernel<<<2048, 256, 0, stream>>>(gu, gub, NEXP * 2 * INTER * HID / 8);
    cvt_kernel<<<2048, 256, 0, stream>>>(dn, dnb, NEXP * HID * INTER / 8);
    router2<<<NTOK / 4, 256, 0, stream>>>(x, rw, route, wslot);
    scatter_kernel<<<1, 1024, 0, stream>>>(route, counts, tokslot, ntiles, tiledesc);
    gateup2p<<<dim3(72, 16), 512, 131072, stream>>>(xb, gub, counts, ntiles, tiledesc, tokslot, hb);
    down2p<<<dim3(72, 3), 512, 131072, stream>>>(hb, dnb, counts, ntiles, tiledesc, tokslot, wslot, out);
}